// Round 1
// baseline (499.501 us; speedup 1.0000x reference)
//
#include <hip/hip_runtime.h>
#include <hip/hip_bf16.h>

#define NN 6144
#define CAP 128

// ---------------------------------------------------------------- sparsify
// One wave per row: scan the dense row, compact nonzeros (ordered) into ELL.
__global__ __launch_bounds__(256) void sparsify_kernel(
    const float* __restrict__ A, int* __restrict__ cols,
    float* __restrict__ vals, int* __restrict__ cnt) {
  int row = (blockIdx.x * blockDim.x + threadIdx.x) >> 6;
  int lane = threadIdx.x & 63;
  if (row >= NN) return;
  const float* arow = A + (size_t)row * NN;
  int base = 0;
  for (int c0 = 0; c0 < NN; c0 += 64) {
    float v = arow[c0 + lane];
    unsigned long long m = __ballot(v != 0.0f);
    if (v != 0.0f) {
      int idx = base + __popcll(m & ((1ull << lane) - 1ull));
      if (idx < CAP) {
        cols[row * CAP + idx] = c0 + lane;
        vals[row * CAP + idx] = v;
      }
    }
    base += __popcll(m);
  }
  if (lane == 0) cnt[row] = base < CAP ? base : CAP;
}

// ---------------------------------------------------------------- transpose (small W)
__global__ __launch_bounds__(256) void transpose_kernel(
    const float* __restrict__ in, float* __restrict__ out, int R, int C) {
  int i = blockIdx.x * blockDim.x + threadIdx.x;
  if (i < R * C) {
    int r = i / C, c = i % C;
    out[c * R + r] = in[i];
  }
}

// ---------------------------------------------------------------- f1/f2 = H @ v1, H @ v2
template <int D>
__global__ __launch_bounds__(256) void fvec_kernel(
    const float* __restrict__ H, const float* __restrict__ v1,
    const float* __restrict__ v2, float* __restrict__ f1, float* __restrict__ f2) {
  int row = (blockIdx.x * blockDim.x + threadIdx.x) >> 6;
  int lane = threadIdx.x & 63;
  if (row >= NN) return;
  float s1 = 0.f, s2 = 0.f;
#pragma unroll
  for (int d = lane; d < D; d += 64) {
    float h = H[row * D + d];
    s1 += h * v1[d];
    s2 += h * v2[d];
  }
#pragma unroll
  for (int o = 32; o; o >>= 1) {
    s1 += __shfl_xor(s1, o);
    s2 += __shfl_xor(s2, o);
  }
  if (lane == 0) { f1[row] = s1; f2[row] = s2; }
}

// ---------------------------------------------------------------- GAT edge softmax
// cvals[i,k] = softmax_k( exp(sigmoid(a_ik * (f1_i + f2_j))) ) over nnz of row i
__global__ __launch_bounds__(256) void gat_kernel(
    const int* __restrict__ cols, const float* __restrict__ avals,
    const int* __restrict__ cnt, const float* __restrict__ f1,
    const float* __restrict__ f2, float* __restrict__ cvals) {
  int row = (blockIdx.x * blockDim.x + threadIdx.x) >> 6;
  int lane = threadIdx.x & 63;
  if (row >= NN) return;
  int c = cnt[row];
  float f1i = f1[row];
  float e[CAP / 64];
  float s = 0.f;
#pragma unroll
  for (int p = 0; p < CAP / 64; ++p) {
    e[p] = 0.f;
    int k = p * 64 + lane;
    if (k < c) {
      float a = avals[row * CAP + k];
      int j = cols[row * CAP + k];
      float logit = a * (f1i + f2[j]);
      float sig = 1.f / (1.f + expf(-logit));
      e[p] = expf(sig);
    }
    s += e[p];
  }
#pragma unroll
  for (int o = 32; o; o >>= 1) s += __shfl_xor(s, o);
  float denom = (s == 0.f) ? 1.f : s;
  float inv = 1.f / denom;
#pragma unroll
  for (int p = 0; p < CAP / 64; ++p) {
    int k = p * 64 + lane;
    if (k < c) cvals[row * CAP + k] = e[p] * inv;
  }
}

// ---------------------------------------------------------------- SPMM: out = C @ H
template <int D>
__global__ __launch_bounds__(256) void spmm_kernel(
    const int* __restrict__ cols, const float* __restrict__ cvals,
    const int* __restrict__ cnt, const float* __restrict__ Hin,
    float* __restrict__ Hout) {
  int row = (blockIdx.x * blockDim.x + threadIdx.x) >> 6;
  int lane = threadIdx.x & 63;
  if (row >= NN) return;
  constexpr int E = D / 64;  // elems per lane (2,4,8)
  int c = cnt[row];
  float acc[E];
#pragma unroll
  for (int i = 0; i < E; ++i) acc[i] = 0.f;
  const int base = row * CAP;
  for (int k = 0; k < c; ++k) {
    float cv = cvals[base + k];
    int j = cols[base + k];
    const float* hp = Hin + (size_t)j * D + lane * E;
    if constexpr (E == 2) {
      float2 h = *(const float2*)hp;
      acc[0] += cv * h.x; acc[1] += cv * h.y;
    } else if constexpr (E == 4) {
      float4 h = *(const float4*)hp;
      acc[0] += cv * h.x; acc[1] += cv * h.y; acc[2] += cv * h.z; acc[3] += cv * h.w;
    } else {
      float4 h0 = *(const float4*)hp;
      float4 h1 = *(const float4*)(hp + 4);
      acc[0] += cv * h0.x; acc[1] += cv * h0.y; acc[2] += cv * h0.z; acc[3] += cv * h0.w;
      acc[4] += cv * h1.x; acc[5] += cv * h1.y; acc[6] += cv * h1.z; acc[7] += cv * h1.w;
    }
  }
  float* op = Hout + (size_t)row * D + lane * E;
  if constexpr (E == 2) {
    *(float2*)op = make_float2(acc[0], acc[1]);
  } else if constexpr (E == 4) {
    *(float4*)op = make_float4(acc[0], acc[1], acc[2], acc[3]);
  } else {
    *(float4*)op = make_float4(acc[0], acc[1], acc[2], acc[3]);
    *(float4*)(op + 4) = make_float4(acc[4], acc[5], acc[6], acc[7]);
  }
}

// ---------------------------------------------------------------- f32 tiled GEMM
// C[M,Nn] = A[M,K] @ B[K,Nn], all row-major. M%64==0, Nn%64==0, K%16==0.
#define BM 64
#define BN 64
#define BK 16
__global__ __launch_bounds__(256) void gemm_f32(
    const float* __restrict__ A, const float* __restrict__ B,
    float* __restrict__ C, int M, int K, int Nn) {
  __shared__ float As[BK][BM + 4];
  __shared__ float Bs[BK][BN + 4];
  int bm = blockIdx.x * BM;
  int bn = blockIdx.y * BN;
  int t = threadIdx.x;
  int tm = (t >> 4) * 4;      // 0..60
  int tn = (t & 15) * 4;      // 0..60
  int la_m = t >> 2;          // 0..63
  int la_k = (t & 3) * 4;     // 0,4,8,12
  int lb_k = t >> 4;          // 0..15
  int lb_n = (t & 15) * 4;    // 0..60
  float acc[4][4] = {};
  for (int k0 = 0; k0 < K; k0 += BK) {
    float4 a4 = *(const float4*)&A[(size_t)(bm + la_m) * K + k0 + la_k];
    float4 b4 = *(const float4*)&B[(size_t)(k0 + lb_k) * Nn + bn + lb_n];
    __syncthreads();
    As[la_k + 0][la_m] = a4.x;
    As[la_k + 1][la_m] = a4.y;
    As[la_k + 2][la_m] = a4.z;
    As[la_k + 3][la_m] = a4.w;
    Bs[lb_k][lb_n + 0] = b4.x;
    Bs[lb_k][lb_n + 1] = b4.y;
    Bs[lb_k][lb_n + 2] = b4.z;
    Bs[lb_k][lb_n + 3] = b4.w;
    __syncthreads();
#pragma unroll
    for (int k = 0; k < BK; ++k) {
      float a0 = As[k][tm + 0], a1 = As[k][tm + 1], a2 = As[k][tm + 2], a3 = As[k][tm + 3];
      float b0 = Bs[k][tn + 0], b1 = Bs[k][tn + 1], b2 = Bs[k][tn + 2], b3 = Bs[k][tn + 3];
      acc[0][0] += a0 * b0; acc[0][1] += a0 * b1; acc[0][2] += a0 * b2; acc[0][3] += a0 * b3;
      acc[1][0] += a1 * b0; acc[1][1] += a1 * b1; acc[1][2] += a1 * b2; acc[1][3] += a1 * b3;
      acc[2][0] += a2 * b0; acc[2][1] += a2 * b1; acc[2][2] += a2 * b2; acc[2][3] += a2 * b3;
      acc[3][0] += a3 * b0; acc[3][1] += a3 * b1; acc[3][2] += a3 * b2; acc[3][3] += a3 * b3;
    }
  }
#pragma unroll
  for (int i = 0; i < 4; ++i)
#pragma unroll
    for (int j = 0; j < 4; ++j)
      C[(size_t)(bm + tm + i) * Nn + bn + tn + j] = acc[i][j];
}

// ---------------------------------------------------------------- final: H_F + student-t q
__global__ __launch_bounds__(256) void final_kernel(
    const float* __restrict__ H1e, const float* __restrict__ H2e,
    const float* __restrict__ mu, float* __restrict__ hf_out,
    float* __restrict__ q_out) {
  int row = (blockIdx.x * blockDim.x + threadIdx.x) >> 6;
  int lane = threadIdx.x & 63;
  if (row >= NN) return;
  float2 h1 = *(const float2*)&H1e[row * 128 + lane * 2];
  float2 h2 = *(const float2*)&H2e[row * 128 + lane * 2];
  float2 hf = make_float2(h1.x + h2.x, h1.y + h2.y);
  *(float2*)&hf_out[row * 128 + lane * 2] = hf;
  float d2[10];
#pragma unroll
  for (int k = 0; k < 10; ++k) {
    float dx = hf.x - mu[k * 128 + lane * 2];
    float dy = hf.y - mu[k * 128 + lane * 2 + 1];
    d2[k] = dx * dx + dy * dy;
  }
#pragma unroll
  for (int k = 0; k < 10; ++k)
#pragma unroll
    for (int o = 32; o; o >>= 1) d2[k] += __shfl_xor(d2[k], o);
  float q[10], s = 0.f;
#pragma unroll
  for (int k = 0; k < 10; ++k) { q[k] = 1.f / (1.f + d2[k]); s += q[k]; }
  float inv = 1.f / s;
  if (lane < 10) q_out[row * 10 + lane] = q[lane] * inv;
}

// ---------------------------------------------------------------- host
extern "C" void kernel_launch(void* const* d_in, const int* in_sizes, int n_in,
                              void* d_out, int out_size, void* d_ws, size_t ws_size,
                              hipStream_t stream) {
  const int D0 = 512, D1 = 256, D2 = 128;
  float* out = (float*)d_out;
  const size_t o0 = 0;                       // H_F  [N,128]
  const size_t o1 = o0 + (size_t)NN * 128;   // q    [N,10]
  const size_t o2 = o1 + (size_t)NN * 10;    // H    [N,128]
  const size_t o3 = o2 + (size_t)NN * 128;   // H2   [N,128]
  const size_t o4 = o3 + (size_t)NN * 128;   // X_   [N,512]
  const size_t o5 = o4 + (size_t)NN * 512;   // X_2  [N,512]

  char* w = (char*)d_ws;
  auto alloc = [&](size_t bytes) -> void* {
    void* p = (void*)w;
    w += (bytes + 255) & ~(size_t)255;
    return p;
  };
  int*   cols  = (int*)  alloc((size_t)NN * CAP * 4);
  float* avals = (float*)alloc((size_t)NN * CAP * 4);
  float* c1v   = (float*)alloc((size_t)NN * CAP * 4);
  float* c2v   = (float*)alloc((size_t)NN * CAP * 4);
  int*   cnt   = (int*)  alloc((size_t)NN * 4);
  float* f1    = (float*)alloc((size_t)NN * 4);
  float* f2    = (float*)alloc((size_t)NN * 4);
  float* H1    = (float*)alloc((size_t)NN * D1 * 4);
  float* H1p   = (float*)alloc((size_t)NN * D1 * 4);
  float* H2    = (float*)alloc((size_t)NN * D2 * 4);
  float* dec1  = (float*)alloc((size_t)NN * D1 * 4);
  float* dec2  = (float*)alloc((size_t)NN * D1 * 4);
  float* dec3  = (float*)alloc((size_t)NN * D0 * 4);
  float* W1T   = (float*)alloc((size_t)D0 * D1 * 4);
  float* W2T   = (float*)alloc((size_t)D1 * D2 * 4);

  const int RPB = 256 / 64;  // rows per block for wave-per-row kernels
  const dim3 rowsGrid(NN / RPB);

  for (int b = 0; b < 2; ++b) {
    const float* A   = (const float*)d_in[b == 0 ? 0 : 1];
    const float* X   = (const float*)d_in[b == 0 ? 2 : 3];
    const float* W1  = (const float*)d_in[b == 0 ? 4 : 10];
    const float* va1 = (const float*)d_in[b == 0 ? 5 : 11];
    const float* va2 = (const float*)d_in[b == 0 ? 6 : 12];
    const float* W2  = (const float*)d_in[b == 0 ? 7 : 13];
    const float* vb1 = (const float*)d_in[b == 0 ? 8 : 14];
    const float* vb2 = (const float*)d_in[b == 0 ? 9 : 15];
    float* Henc = out + (b == 0 ? o2 : o3);
    float* Xrec = out + (b == 0 ? o4 : o5);

    transpose_kernel<<<(D0 * D1 + 255) / 256, 256, 0, stream>>>(W1, W1T, D0, D1);
    transpose_kernel<<<(D1 * D2 + 255) / 256, 256, 0, stream>>>(W2, W2T, D1, D2);
    sparsify_kernel<<<rowsGrid, 256, 0, stream>>>(A, cols, avals, cnt);

    // encoder layer 1
    gemm_f32<<<dim3(NN / BM, D1 / BN), 256, 0, stream>>>(X, W1, H1, NN, D0, D1);
    fvec_kernel<256><<<rowsGrid, 256, 0, stream>>>(H1, va1, va2, f1, f2);
    gat_kernel<<<rowsGrid, 256, 0, stream>>>(cols, avals, cnt, f1, f2, c1v);
    spmm_kernel<256><<<rowsGrid, 256, 0, stream>>>(cols, c1v, cnt, H1, H1p);

    // encoder layer 2
    gemm_f32<<<dim3(NN / BM, D2 / BN), 256, 0, stream>>>(H1p, W2, H2, NN, D1, D2);
    fvec_kernel<128><<<rowsGrid, 256, 0, stream>>>(H2, vb1, vb2, f1, f2);
    gat_kernel<<<rowsGrid, 256, 0, stream>>>(cols, avals, cnt, f1, f2, c2v);
    spmm_kernel<128><<<rowsGrid, 256, 0, stream>>>(cols, c2v, cnt, H2, Henc);

    // decoder
    gemm_f32<<<dim3(NN / BM, D1 / BN), 256, 0, stream>>>(Henc, W2T, dec1, NN, D2, D1);
    spmm_kernel<256><<<rowsGrid, 256, 0, stream>>>(cols, c2v, cnt, dec1, dec2);
    gemm_f32<<<dim3(NN / BM, D0 / BN), 256, 0, stream>>>(dec2, W1T, dec3, NN, D1, D0);
    spmm_kernel<512><<<rowsGrid, 256, 0, stream>>>(cols, c1v, cnt, dec3, Xrec);
  }

  const float* mu = (const float*)d_in[16];
  final_kernel<<<rowsGrid, 256, 0, stream>>>(out + o2, out + o3, mu, out + o0, out + o1);
}

// Round 2
// 442.960 us; speedup vs baseline: 1.1276x; 1.1276x over previous
//
#include <hip/hip_runtime.h>
#include <hip/hip_bf16.h>

#define NN 6144
#define CAP 128

typedef short bf8 __attribute__((ext_vector_type(8)));
typedef float f4 __attribute__((ext_vector_type(4)));

__device__ inline unsigned short f2bf(float x) {
  union { float f; unsigned u; } v; v.f = x;
  unsigned r = v.u + 0x7fff + ((v.u >> 16) & 1);
  return (unsigned short)(r >> 16);
}
__device__ inline float bf2f(unsigned short b) {
  union { float f; unsigned u; } v; v.u = ((unsigned)b) << 16;
  return v.f;
}

// ---------------------------------------------------------------- sparsify
__global__ __launch_bounds__(256) void sparsify_kernel(
    const float* __restrict__ A, int* __restrict__ cols,
    float* __restrict__ vals, int* __restrict__ cnt) {
  int row = (blockIdx.x * blockDim.x + threadIdx.x) >> 6;
  int lane = threadIdx.x & 63;
  if (row >= NN) return;
  const float* arow = A + (size_t)row * NN;
  int base = 0;
  for (int c0 = 0; c0 < NN; c0 += 64) {
    float v = arow[c0 + lane];
    unsigned long long m = __ballot(v != 0.0f);
    if (v != 0.0f) {
      int idx = base + __popcll(m & ((1ull << lane) - 1ull));
      if (idx < CAP) {
        cols[row * CAP + idx] = c0 + lane;
        vals[row * CAP + idx] = v;
      }
    }
    base += __popcll(m);
  }
  if (lane == 0) cnt[row] = base < CAP ? base : CAP;
}

// ---------------------------------------------------------------- hi/lo split converts
__global__ __launch_bounds__(256) void conv_hilo(
    const float* __restrict__ in, short* __restrict__ hi,
    short* __restrict__ lo, int n4) {
  int i = blockIdx.x * blockDim.x + threadIdx.x;
  if (i >= n4) return;
  float4 v = *(const float4*)&in[i * 4];
  short4 h, l;
  h.x = (short)f2bf(v.x); l.x = (short)f2bf(v.x - bf2f(h.x));
  h.y = (short)f2bf(v.y); l.y = (short)f2bf(v.y - bf2f(h.y));
  h.z = (short)f2bf(v.z); l.z = (short)f2bf(v.z - bf2f(h.z));
  h.w = (short)f2bf(v.w); l.w = (short)f2bf(v.w - bf2f(h.w));
  *(short4*)&hi[i * 4] = h;
  *(short4*)&lo[i * 4] = l;
}

// convert weight to hi/lo, both row-major [R,C] and transposed [C,R]
__global__ __launch_bounds__(256) void convw_kernel(
    const float* __restrict__ in, short* __restrict__ h, short* __restrict__ l,
    short* __restrict__ th, short* __restrict__ tl, int R, int C) {
  int i = blockIdx.x * blockDim.x + threadIdx.x;
  if (i >= R * C) return;
  float x = in[i];
  unsigned short hh = f2bf(x);
  unsigned short ll = f2bf(x - bf2f(hh));
  int r = i / C, c = i % C;
  h[i] = (short)hh; l[i] = (short)ll;
  th[c * R + r] = (short)hh; tl[c * R + r] = (short)ll;
}

// ---------------------------------------------------------------- f1/f2 = H @ v1, H @ v2
template <int D>
__global__ __launch_bounds__(256) void fvec_kernel(
    const float* __restrict__ H, const float* __restrict__ v1,
    const float* __restrict__ v2, float* __restrict__ f1, float* __restrict__ f2) {
  int row = (blockIdx.x * blockDim.x + threadIdx.x) >> 6;
  int lane = threadIdx.x & 63;
  if (row >= NN) return;
  float s1 = 0.f, s2 = 0.f;
#pragma unroll
  for (int d = lane; d < D; d += 64) {
    float h = H[row * D + d];
    s1 += h * v1[d];
    s2 += h * v2[d];
  }
#pragma unroll
  for (int o = 32; o; o >>= 1) {
    s1 += __shfl_xor(s1, o);
    s2 += __shfl_xor(s2, o);
  }
  if (lane == 0) { f1[row] = s1; f2[row] = s2; }
}

// ---------------------------------------------------------------- GAT edge softmax
__global__ __launch_bounds__(256) void gat_kernel(
    const int* __restrict__ cols, const float* __restrict__ avals,
    const int* __restrict__ cnt, const float* __restrict__ f1,
    const float* __restrict__ f2, float* __restrict__ cvals) {
  int row = (blockIdx.x * blockDim.x + threadIdx.x) >> 6;
  int lane = threadIdx.x & 63;
  if (row >= NN) return;
  int c = cnt[row];
  float f1i = f1[row];
  float e[CAP / 64];
  float s = 0.f;
#pragma unroll
  for (int p = 0; p < CAP / 64; ++p) {
    e[p] = 0.f;
    int k = p * 64 + lane;
    if (k < c) {
      float a = avals[row * CAP + k];
      int j = cols[row * CAP + k];
      float logit = a * (f1i + f2[j]);
      float sig = 1.f / (1.f + expf(-logit));
      e[p] = expf(sig);
    }
    s += e[p];
  }
#pragma unroll
  for (int o = 32; o; o >>= 1) s += __shfl_xor(s, o);
  float denom = (s == 0.f) ? 1.f : s;
  float inv = 1.f / denom;
#pragma unroll
  for (int p = 0; p < CAP / 64; ++p) {
    int k = p * 64 + lane;
    if (k < c) cvals[row * CAP + k] = e[p] * inv;
  }
}

// ---------------------------------------------------------------- SPMM: out = C @ H
template <int D>
__global__ __launch_bounds__(256) void spmm_kernel(
    const int* __restrict__ cols, const float* __restrict__ cvals,
    const int* __restrict__ cnt, const float* __restrict__ Hin,
    float* __restrict__ Hout) {
  int row = (blockIdx.x * blockDim.x + threadIdx.x) >> 6;
  int lane = threadIdx.x & 63;
  if (row >= NN) return;
  constexpr int E = D / 64;
  int c = cnt[row];
  float acc[E];
#pragma unroll
  for (int i = 0; i < E; ++i) acc[i] = 0.f;
  const int base = row * CAP;
  for (int k = 0; k < c; ++k) {
    float cv = cvals[base + k];
    int j = cols[base + k];
    const float* hp = Hin + (size_t)j * D + lane * E;
    if constexpr (E == 2) {
      float2 h = *(const float2*)hp;
      acc[0] += cv * h.x; acc[1] += cv * h.y;
    } else if constexpr (E == 4) {
      float4 h = *(const float4*)hp;
      acc[0] += cv * h.x; acc[1] += cv * h.y; acc[2] += cv * h.z; acc[3] += cv * h.w;
    } else {
      float4 h0 = *(const float4*)hp;
      float4 h1 = *(const float4*)(hp + 4);
      acc[0] += cv * h0.x; acc[1] += cv * h0.y; acc[2] += cv * h0.z; acc[3] += cv * h0.w;
      acc[4] += cv * h1.x; acc[5] += cv * h1.y; acc[6] += cv * h1.z; acc[7] += cv * h1.w;
    }
  }
  float* op = Hout + (size_t)row * D + lane * E;
  if constexpr (E == 2) {
    *(float2*)op = make_float2(acc[0], acc[1]);
  } else if constexpr (E == 4) {
    *(float4*)op = make_float4(acc[0], acc[1], acc[2], acc[3]);
  } else {
    *(float4*)op = make_float4(acc[0], acc[1], acc[2], acc[3]);
    *(float4*)(op + 4) = make_float4(acc[4], acc[5], acc[6], acc[7]);
  }
}

// ---------------------------------------------------------------- split-bf16 MFMA GEMM (NT)
// C[M,Nn] = A[M,K] @ Bt[Nn,K]^T ; A,Bt as hi/lo bf16 row-major; C f32.
// 64x64 tile, BK=32, 4 waves, each wave 32x32 (2x2 of 16x16x32 frags).
#define GS 40  // LDS row stride in shorts (pad 32->40: 2-way bank alias only, 16B aligned)
#define MFMA_BF16 __builtin_amdgcn_mfma_f32_16x16x32_bf16

__global__ __launch_bounds__(256) void gemm_nt(
    const short* __restrict__ Ahg, const short* __restrict__ Alg,
    const short* __restrict__ Bhg, const short* __restrict__ Blg,
    float* __restrict__ C, int M, int K, int Nn) {
  __shared__ short sAh[64 * GS], sAl[64 * GS], sBh[64 * GS], sBl[64 * GS];
  const int bm = blockIdx.x * 64, bn = blockIdx.y * 64;
  const int t = threadIdx.x;
  const int lane = t & 63, w = t >> 6;
  const int wm = (w & 1) * 32, wn = (w >> 1) * 32;
  const int fr = lane & 15, fq = lane >> 4;
  const int srow = t >> 2, sk = (t & 3) * 8;  // staging: 64 rows x 32 k, short8 per thread

  f4 acc[2][2] = {};

  for (int k0 = 0; k0 < K; k0 += 32) {
    const size_t aoff = (size_t)(bm + srow) * K + k0 + sk;
    const size_t boff = (size_t)(bn + srow) * K + k0 + sk;
    bf8 vah = *(const bf8*)&Ahg[aoff];
    bf8 val_ = *(const bf8*)&Alg[aoff];
    bf8 vbh = *(const bf8*)&Bhg[boff];
    bf8 vbl = *(const bf8*)&Blg[boff];
    __syncthreads();
    *(bf8*)&sAh[srow * GS + sk] = vah;
    *(bf8*)&sAl[srow * GS + sk] = val_;
    *(bf8*)&sBh[srow * GS + sk] = vbh;
    *(bf8*)&sBl[srow * GS + sk] = vbl;
    __syncthreads();

    bf8 ah[2], al[2], bh[2], bl[2];
#pragma unroll
    for (int i = 0; i < 2; ++i) {
      ah[i] = *(bf8*)&sAh[(wm + i * 16 + fr) * GS + fq * 8];
      al[i] = *(bf8*)&sAl[(wm + i * 16 + fr) * GS + fq * 8];
      bh[i] = *(bf8*)&sBh[(wn + i * 16 + fr) * GS + fq * 8];
      bl[i] = *(bf8*)&sBl[(wn + i * 16 + fr) * GS + fq * 8];
    }
#pragma unroll
    for (int mi = 0; mi < 2; ++mi)
#pragma unroll
      for (int ni = 0; ni < 2; ++ni) {
        acc[mi][ni] = MFMA_BF16(ah[mi], bh[ni], acc[mi][ni], 0, 0, 0);
        acc[mi][ni] = MFMA_BF16(ah[mi], bl[ni], acc[mi][ni], 0, 0, 0);
        acc[mi][ni] = MFMA_BF16(al[mi], bh[ni], acc[mi][ni], 0, 0, 0);
      }
  }

#pragma unroll
  for (int mi = 0; mi < 2; ++mi)
#pragma unroll
    for (int ni = 0; ni < 2; ++ni) {
      size_t rbase = (size_t)(bm + wm + mi * 16 + fq * 4);
      int cidx = bn + wn + ni * 16 + fr;
#pragma unroll
      for (int r = 0; r < 4; ++r)
        C[(rbase + r) * Nn + cidx] = acc[mi][ni][r];
    }
}

// ---------------------------------------------------------------- final: H_F + student-t q
__global__ __launch_bounds__(256) void final_kernel(
    const float* __restrict__ H1e, const float* __restrict__ H2e,
    const float* __restrict__ mu, float* __restrict__ hf_out,
    float* __restrict__ q_out) {
  int row = (blockIdx.x * blockDim.x + threadIdx.x) >> 6;
  int lane = threadIdx.x & 63;
  if (row >= NN) return;
  float2 h1 = *(const float2*)&H1e[row * 128 + lane * 2];
  float2 h2 = *(const float2*)&H2e[row * 128 + lane * 2];
  float2 hf = make_float2(h1.x + h2.x, h1.y + h2.y);
  *(float2*)&hf_out[row * 128 + lane * 2] = hf;
  float d2[10];
#pragma unroll
  for (int k = 0; k < 10; ++k) {
    float dx = hf.x - mu[k * 128 + lane * 2];
    float dy = hf.y - mu[k * 128 + lane * 2 + 1];
    d2[k] = dx * dx + dy * dy;
  }
#pragma unroll
  for (int k = 0; k < 10; ++k)
#pragma unroll
    for (int o = 32; o; o >>= 1) d2[k] += __shfl_xor(d2[k], o);
  float q[10], s = 0.f;
#pragma unroll
  for (int k = 0; k < 10; ++k) { q[k] = 1.f / (1.f + d2[k]); s += q[k]; }
  float inv = 1.f / s;
  if (lane < 10) q_out[row * 10 + lane] = q[lane] * inv;
}

// ---------------------------------------------------------------- host
extern "C" void kernel_launch(void* const* d_in, const int* in_sizes, int n_in,
                              void* d_out, int out_size, void* d_ws, size_t ws_size,
                              hipStream_t stream) {
  const int D0 = 512, D1 = 256, D2 = 128;
  float* out = (float*)d_out;
  const size_t o0 = 0;                       // H_F  [N,128]
  const size_t o1 = o0 + (size_t)NN * 128;   // q    [N,10]
  const size_t o2 = o1 + (size_t)NN * 10;    // H    [N,128]
  const size_t o3 = o2 + (size_t)NN * 128;   // H2   [N,128]
  const size_t o4 = o3 + (size_t)NN * 128;   // X_   [N,512]
  const size_t o5 = o4 + (size_t)NN * 512;   // X_2  [N,512]

  char* w = (char*)d_ws;
  auto alloc = [&](size_t bytes) -> void* {
    void* p = (void*)w;
    w += (bytes + 255) & ~(size_t)255;
    return p;
  };
  int*   cols  = (int*)  alloc((size_t)NN * CAP * 4);
  float* avals = (float*)alloc((size_t)NN * CAP * 4);
  float* c1v   = (float*)alloc((size_t)NN * CAP * 4);
  float* c2v   = (float*)alloc((size_t)NN * CAP * 4);
  int*   cnt   = (int*)  alloc((size_t)NN * 4);
  float* f1    = (float*)alloc((size_t)NN * 4);
  float* f2    = (float*)alloc((size_t)NN * 4);
  float* H1    = (float*)alloc((size_t)NN * D1 * 4);
  float* H1p   = (float*)alloc((size_t)NN * D1 * 4);
  float* H2    = (float*)alloc((size_t)NN * D2 * 4);
  float* dec1  = (float*)alloc((size_t)NN * D1 * 4);
  float* dec2  = (float*)alloc((size_t)NN * D1 * 4);
  float* dec3  = (float*)alloc((size_t)NN * D0 * 4);
  // split-bf16 buffers
  short* Xh   = (short*)alloc((size_t)NN * D0 * 2);
  short* Xl   = (short*)alloc((size_t)NN * D0 * 2);
  short* H1ph = (short*)alloc((size_t)NN * D1 * 2);
  short* H1pl = (short*)alloc((size_t)NN * D1 * 2);
  short* Hech = (short*)alloc((size_t)NN * D2 * 2);
  short* Hecl = (short*)alloc((size_t)NN * D2 * 2);
  short* d2h  = (short*)alloc((size_t)NN * D1 * 2);
  short* d2l  = (short*)alloc((size_t)NN * D1 * 2);
  short* W1h  = (short*)alloc((size_t)D0 * D1 * 2);
  short* W1l  = (short*)alloc((size_t)D0 * D1 * 2);
  short* W1th = (short*)alloc((size_t)D0 * D1 * 2);
  short* W1tl = (short*)alloc((size_t)D0 * D1 * 2);
  short* W2h  = (short*)alloc((size_t)D1 * D2 * 2);
  short* W2l  = (short*)alloc((size_t)D1 * D2 * 2);
  short* W2th = (short*)alloc((size_t)D1 * D2 * 2);
  short* W2tl = (short*)alloc((size_t)D1 * D2 * 2);

  const dim3 rowsGrid(NN / 4);  // 4 waves of one row each per block

  for (int b = 0; b < 2; ++b) {
    const float* A   = (const float*)d_in[b == 0 ? 0 : 1];
    const float* X   = (const float*)d_in[b == 0 ? 2 : 3];
    const float* W1  = (const float*)d_in[b == 0 ? 4 : 10];
    const float* va1 = (const float*)d_in[b == 0 ? 5 : 11];
    const float* va2 = (const float*)d_in[b == 0 ? 6 : 12];
    const float* W2  = (const float*)d_in[b == 0 ? 7 : 13];
    const float* vb1 = (const float*)d_in[b == 0 ? 8 : 14];
    const float* vb2 = (const float*)d_in[b == 0 ? 9 : 15];
    float* Henc = out + (b == 0 ? o2 : o3);
    float* Xrec = out + (b == 0 ? o4 : o5);

    convw_kernel<<<(D0 * D1 + 255) / 256, 256, 0, stream>>>(W1, W1h, W1l, W1th, W1tl, D0, D1);
    convw_kernel<<<(D1 * D2 + 255) / 256, 256, 0, stream>>>(W2, W2h, W2l, W2th, W2tl, D1, D2);
    sparsify_kernel<<<rowsGrid, 256, 0, stream>>>(A, cols, avals, cnt);
    conv_hilo<<<(NN * D0 / 4 + 255) / 256, 256, 0, stream>>>(X, Xh, Xl, NN * D0 / 4);

    // encoder layer 1: H1 = X @ W1
    gemm_nt<<<dim3(NN / 64, D1 / 64), 256, 0, stream>>>(Xh, Xl, W1th, W1tl, H1, NN, D0, D1);
    fvec_kernel<256><<<rowsGrid, 256, 0, stream>>>(H1, va1, va2, f1, f2);
    gat_kernel<<<rowsGrid, 256, 0, stream>>>(cols, avals, cnt, f1, f2, c1v);
    spmm_kernel<256><<<rowsGrid, 256, 0, stream>>>(cols, c1v, cnt, H1, H1p);

    // encoder layer 2: H2 = H1p @ W2
    conv_hilo<<<(NN * D1 / 4 + 255) / 256, 256, 0, stream>>>(H1p, H1ph, H1pl, NN * D1 / 4);
    gemm_nt<<<dim3(NN / 64, D2 / 64), 256, 0, stream>>>(H1ph, H1pl, W2th, W2tl, H2, NN, D1, D2);
    fvec_kernel<128><<<rowsGrid, 256, 0, stream>>>(H2, vb1, vb2, f1, f2);
    gat_kernel<<<rowsGrid, 256, 0, stream>>>(cols, avals, cnt, f1, f2, c2v);
    spmm_kernel<128><<<rowsGrid, 256, 0, stream>>>(cols, c2v, cnt, H2, Henc);

    // decoder: dec1 = Henc @ W2^T  (Bt = W2 row-major)
    conv_hilo<<<(NN * D2 / 4 + 255) / 256, 256, 0, stream>>>(Henc, Hech, Hecl, NN * D2 / 4);
    gemm_nt<<<dim3(NN / 64, D1 / 64), 256, 0, stream>>>(Hech, Hecl, W2h, W2l, dec1, NN, D2, D1);
    spmm_kernel<256><<<rowsGrid, 256, 0, stream>>>(cols, c2v, cnt, dec1, dec2);
    // dec3 = dec2 @ W1^T  (Bt = W1 row-major)
    conv_hilo<<<(NN * D1 / 4 + 255) / 256, 256, 0, stream>>>(dec2, d2h, d2l, NN * D1 / 4);
    gemm_nt<<<dim3(NN / 64, D0 / 64), 256, 0, stream>>>(d2h, d2l, W1h, W1l, dec3, NN, D1, D0);
    spmm_kernel<512><<<rowsGrid, 256, 0, stream>>>(cols, c1v, cnt, dec3, Xrec);
  }

  const float* mu = (const float*)d_in[16];
  final_kernel<<<rowsGrid, 256, 0, stream>>>(out + o2, out + o3, mu, out + o0, out + o1);
}

// Round 3
// 317.090 us; speedup vs baseline: 1.5753x; 1.3970x over previous
//
#include <hip/hip_runtime.h>
#include <hip/hip_bf16.h>

#define NN 6144
#define CAP 128

typedef short bf8 __attribute__((ext_vector_type(8)));
typedef float f4 __attribute__((ext_vector_type(4)));

__device__ inline unsigned short f2bf(float x) {
  union { float f; unsigned u; } v; v.f = x;
  unsigned r = v.u + 0x7fff + ((v.u >> 16) & 1);
  return (unsigned short)(r >> 16);
}
__device__ inline float bf2f(unsigned short b) {
  union { float f; unsigned u; } v; v.u = ((unsigned)b) << 16;
  return v.f;
}

// ---------------------------------------------------------------- sparsify (both branches, float4 loads)
__global__ __launch_bounds__(256) void sparsify2_kernel(
    const float* __restrict__ A0, const float* __restrict__ A1,
    int* __restrict__ colsB, float* __restrict__ valsB, int* __restrict__ cntB) {
  const int br = blockIdx.y;
  const float* __restrict__ A = br ? A1 : A0;
  int* cols = colsB + (size_t)br * NN * CAP;
  float* vals = valsB + (size_t)br * NN * CAP;
  int* cnt = cntB + br * NN;
  int row = (blockIdx.x * blockDim.x + threadIdx.x) >> 6;
  int lane = threadIdx.x & 63;
  const float4* __restrict__ arow = (const float4*)(A + (size_t)row * NN);
  int base = 0;
  for (int it = 0; it < NN / 256; ++it) {  // 24 iters, 1KB/wave/iter
    float4 v = arow[it * 64 + lane];
    float xs[4] = {v.x, v.y, v.z, v.w};
#pragma unroll
    for (int q = 0; q < 4; ++q) {
      float x = xs[q];
      unsigned long long m = __ballot(x != 0.0f);
      if (x != 0.0f) {
        int idx = base + __popcll(m & ((1ull << lane) - 1ull));
        if (idx < CAP) {
          cols[row * CAP + idx] = (it * 64 + lane) * 4 + q;
          vals[row * CAP + idx] = x;
        }
      }
      base += __popcll(m);
    }
  }
  if (lane == 0) cnt[row] = base < CAP ? base : CAP;
}

// ---------------------------------------------------------------- all weights -> hi/lo (+transposed)
__global__ __launch_bounds__(256) void convw_all(
    const float* __restrict__ W11, const float* __restrict__ W21,
    const float* __restrict__ W12, const float* __restrict__ W22,
    short* __restrict__ W1h, short* __restrict__ W1l,
    short* __restrict__ W1th, short* __restrict__ W1tl,
    short* __restrict__ W2h, short* __restrict__ W2l,
    short* __restrict__ W2th, short* __restrict__ W2tl) {
  const int S1 = 512 * 256, S2 = 256 * 128;
  int i = blockIdx.x * 256 + threadIdx.x;
  if (i < 2 * S1) {
    int br = i >= S1;
    int idx = br ? i - S1 : i;
    float x = (br ? W21 : W11)[idx];
    unsigned short h = f2bf(x), l = f2bf(x - bf2f(h));
    int r = idx / 256, c = idx % 256;
    size_t o = (size_t)br * S1;
    W1h[o + idx] = (short)h; W1l[o + idx] = (short)l;
    W1th[o + c * 512 + r] = (short)h; W1tl[o + c * 512 + r] = (short)l;
  } else {
    int i2 = i - 2 * S1;
    if (i2 >= 2 * S2) return;
    int br = i2 >= S2;
    int idx = br ? i2 - S2 : i2;
    float x = (br ? W22 : W12)[idx];
    unsigned short h = f2bf(x), l = f2bf(x - bf2f(h));
    int r = idx / 128, c = idx % 128;
    size_t o = (size_t)br * S2;
    W2h[o + idx] = (short)h; W2l[o + idx] = (short)l;
    W2th[o + c * 256 + r] = (short)h; W2tl[o + c * 256 + r] = (short)l;
  }
}

// ---------------------------------------------------------------- X, X2 -> hi/lo
__global__ __launch_bounds__(256) void convX_kernel(
    const float* __restrict__ X0, const float* __restrict__ X1,
    short* __restrict__ XhB, short* __restrict__ XlB) {
  const int br = blockIdx.y;
  const float* __restrict__ in = br ? X1 : X0;
  short* hi = XhB + (size_t)br * NN * 512;
  short* lo = XlB + (size_t)br * NN * 512;
  int i = blockIdx.x * 256 + threadIdx.x;  // one float4 per thread
  float4 v = *(const float4*)&in[i * 4];
  short4 h, l;
  h.x = (short)f2bf(v.x); l.x = (short)f2bf(v.x - bf2f(h.x));
  h.y = (short)f2bf(v.y); l.y = (short)f2bf(v.y - bf2f(h.y));
  h.z = (short)f2bf(v.z); l.z = (short)f2bf(v.z - bf2f(h.z));
  h.w = (short)f2bf(v.w); l.w = (short)f2bf(v.w - bf2f(h.w));
  *(short4*)&hi[i * 4] = h;
  *(short4*)&lo[i * 4] = l;
}

// ---------------------------------------------------------------- f1/f2 = H @ v1, H @ v2 (both branches)
template <int D>
__global__ __launch_bounds__(256) void fvec_kernel(
    const float* __restrict__ HB, const float* __restrict__ v10,
    const float* __restrict__ v20, const float* __restrict__ v11,
    const float* __restrict__ v21, float* __restrict__ f1B, float* __restrict__ f2B) {
  const int br = blockIdx.y;
  const float* H = HB + (size_t)br * NN * D;
  const float* v1 = br ? v11 : v10;
  const float* v2 = br ? v21 : v20;
  float* f1 = f1B + br * NN;
  float* f2 = f2B + br * NN;
  int row = (blockIdx.x * blockDim.x + threadIdx.x) >> 6;
  int lane = threadIdx.x & 63;
  constexpr int E = D / 64;
  const float* hp = H + (size_t)row * D + lane * E;
  float s1 = 0.f, s2 = 0.f;
  if constexpr (E == 4) {
    float4 h = *(const float4*)hp;
    float4 a = *(const float4*)&v1[lane * 4];
    float4 b = *(const float4*)&v2[lane * 4];
    s1 = h.x * a.x + h.y * a.y + h.z * a.z + h.w * a.w;
    s2 = h.x * b.x + h.y * b.y + h.z * b.z + h.w * b.w;
  } else {
    float2 h = *(const float2*)hp;
    float2 a = *(const float2*)&v1[lane * 2];
    float2 b = *(const float2*)&v2[lane * 2];
    s1 = h.x * a.x + h.y * a.y;
    s2 = h.x * b.x + h.y * b.y;
  }
#pragma unroll
  for (int o = 32; o; o >>= 1) {
    s1 += __shfl_xor(s1, o);
    s2 += __shfl_xor(s2, o);
  }
  if (lane == 0) { f1[row] = s1; f2[row] = s2; }
}

// ---------------------------------------------------------------- fused GAT softmax + SPMM
// Computes row attention in registers, writes cvals (decoder reuse), then Hout = C @ Hin.
template <int D, bool WF32>
__global__ __launch_bounds__(256) void gatspmm_kernel(
    const int* __restrict__ colsB, const float* __restrict__ avalsB,
    const int* __restrict__ cntB, const float* __restrict__ f1B,
    const float* __restrict__ f2B, float* __restrict__ cvalsB,
    const float* __restrict__ HinB, float* __restrict__ Hout0,
    float* __restrict__ Hout1, short* __restrict__ HhB, short* __restrict__ HlB) {
  constexpr int E = D / 64;
  const int br = blockIdx.y;
  const int* cols = colsB + (size_t)br * NN * CAP;
  const float* avals = avalsB + (size_t)br * NN * CAP;
  const int* cnt = cntB + br * NN;
  const float* f1 = f1B + br * NN;
  const float* f2 = f2B + br * NN;
  float* cvals = cvalsB + (size_t)br * NN * CAP;
  const float* Hin = HinB + (size_t)br * NN * D;
  short* Hh = HhB + (size_t)br * NN * D;
  short* Hl = HlB + (size_t)br * NN * D;
  int row = (blockIdx.x * blockDim.x + threadIdx.x) >> 6;
  int lane = threadIdx.x & 63;
  int c = cnt[row];
  float f1i = f1[row];
  const int base = row * CAP;
  float ev[2];
  int jreg[2];
  float s = 0.f;
#pragma unroll
  for (int p = 0; p < 2; ++p) {
    int k = p * 64 + lane;
    ev[p] = 0.f; jreg[p] = 0;
    if (k < c) {
      float a = avals[base + k];
      int j = cols[base + k];
      jreg[p] = j;
      float lg = a * (f1i + f2[j]);
      float sg = 1.f / (1.f + expf(-lg));
      ev[p] = expf(sg);
    }
    s += ev[p];
  }
#pragma unroll
  for (int o = 32; o; o >>= 1) s += __shfl_xor(s, o);
  float inv = (s == 0.f) ? 1.f : 1.f / s;
#pragma unroll
  for (int p = 0; p < 2; ++p) {
    int k = p * 64 + lane;
    if (k < c) cvals[base + k] = ev[p] * inv;
  }
  float acc[E];
#pragma unroll
  for (int i = 0; i < E; ++i) acc[i] = 0.f;
  for (int k = 0; k < c; ++k) {
    int p = k >> 6, sl = k & 63;
    float cv = __shfl(ev[p], sl) * inv;
    int j = __shfl(jreg[p], sl);
    const float* hp = Hin + (size_t)j * D + lane * E;
    if constexpr (E == 2) {
      float2 h = *(const float2*)hp;
      acc[0] += cv * h.x; acc[1] += cv * h.y;
    } else {
      float4 h = *(const float4*)hp;
      acc[0] += cv * h.x; acc[1] += cv * h.y; acc[2] += cv * h.z; acc[3] += cv * h.w;
    }
  }
  size_t o = (size_t)row * D + lane * E;
  if constexpr (WF32) {
    float* Hout = br ? Hout1 : Hout0;
    if constexpr (E == 2) *(float2*)&Hout[o] = make_float2(acc[0], acc[1]);
    else *(float4*)&Hout[o] = make_float4(acc[0], acc[1], acc[2], acc[3]);
  }
  short4 hh, ll;
  short2 h2, l2;
  if constexpr (E == 2) {
    h2.x = (short)f2bf(acc[0]); l2.x = (short)f2bf(acc[0] - bf2f(h2.x));
    h2.y = (short)f2bf(acc[1]); l2.y = (short)f2bf(acc[1] - bf2f(h2.y));
    *(short2*)&Hh[o] = h2; *(short2*)&Hl[o] = l2;
  } else {
    hh.x = (short)f2bf(acc[0]); ll.x = (short)f2bf(acc[0] - bf2f(hh.x));
    hh.y = (short)f2bf(acc[1]); ll.y = (short)f2bf(acc[1] - bf2f(hh.y));
    hh.z = (short)f2bf(acc[2]); ll.z = (short)f2bf(acc[2] - bf2f(hh.z));
    hh.w = (short)f2bf(acc[3]); ll.w = (short)f2bf(acc[3] - bf2f(hh.w));
    *(short4*)&Hh[o] = hh; *(short4*)&Hl[o] = ll;
  }
}

// ---------------------------------------------------------------- SPMM (decoder): out = C @ Hin
template <int D, bool WF32, bool WHL>
__global__ __launch_bounds__(256) void spmm_kernel(
    const int* __restrict__ colsB, const float* __restrict__ cvalsB,
    const int* __restrict__ cntB, const float* __restrict__ HinB,
    float* __restrict__ Hout0, float* __restrict__ Hout1,
    short* __restrict__ HhB, short* __restrict__ HlB) {
  constexpr int E = D / 64;
  const int br = blockIdx.y;
  const int* cols = colsB + (size_t)br * NN * CAP;
  const float* cvals = cvalsB + (size_t)br * NN * CAP;
  const int* cnt = cntB + br * NN;
  const float* Hin = HinB + (size_t)br * NN * D;
  int row = (blockIdx.x * blockDim.x + threadIdx.x) >> 6;
  int lane = threadIdx.x & 63;
  int c = cnt[row];
  float acc[E];
#pragma unroll
  for (int i = 0; i < E; ++i) acc[i] = 0.f;
  const int base = row * CAP;
  for (int k = 0; k < c; ++k) {
    float cv = cvals[base + k];
    int j = cols[base + k];
    const float* hp = Hin + (size_t)j * D + lane * E;
    if constexpr (E == 4) {
      float4 h = *(const float4*)hp;
      acc[0] += cv * h.x; acc[1] += cv * h.y; acc[2] += cv * h.z; acc[3] += cv * h.w;
    } else {
      float4 h0 = *(const float4*)hp;
      float4 h1 = *(const float4*)(hp + 4);
      acc[0] += cv * h0.x; acc[1] += cv * h0.y; acc[2] += cv * h0.z; acc[3] += cv * h0.w;
      acc[4] += cv * h1.x; acc[5] += cv * h1.y; acc[6] += cv * h1.z; acc[7] += cv * h1.w;
    }
  }
  size_t o = (size_t)row * D + lane * E;
  if constexpr (WF32) {
    float* Hout = br ? Hout1 : Hout0;
    if constexpr (E == 4) {
      *(float4*)&Hout[o] = make_float4(acc[0], acc[1], acc[2], acc[3]);
    } else {
      *(float4*)&Hout[o] = make_float4(acc[0], acc[1], acc[2], acc[3]);
      *(float4*)&Hout[o + 4] = make_float4(acc[4], acc[5], acc[6], acc[7]);
    }
  }
  if constexpr (WHL) {
    short* Hh = HhB + (size_t)br * NN * D;
    short* Hl = HlB + (size_t)br * NN * D;
    short4 hh, ll;
#pragma unroll
    for (int g = 0; g < E / 4; ++g) {
      hh.x = (short)f2bf(acc[g * 4 + 0]); ll.x = (short)f2bf(acc[g * 4 + 0] - bf2f(hh.x));
      hh.y = (short)f2bf(acc[g * 4 + 1]); ll.y = (short)f2bf(acc[g * 4 + 1] - bf2f(hh.y));
      hh.z = (short)f2bf(acc[g * 4 + 2]); ll.z = (short)f2bf(acc[g * 4 + 2] - bf2f(hh.z));
      hh.w = (short)f2bf(acc[g * 4 + 3]); ll.w = (short)f2bf(acc[g * 4 + 3] - bf2f(hh.w));
      *(short4*)&Hh[o + g * 4] = hh;
      *(short4*)&Hl[o + g * 4] = ll;
    }
  }
}

// ---------------------------------------------------------------- split-bf16 MFMA GEMM (NT, batched)
#define GS 40
#define MFMA_BF16 __builtin_amdgcn_mfma_f32_16x16x32_bf16

__global__ __launch_bounds__(256) void gemm_nt(
    const short* __restrict__ AhB, const short* __restrict__ AlB, size_t sA,
    const short* __restrict__ BhB, const short* __restrict__ BlB, size_t sB,
    float* __restrict__ CB, size_t sC, int M, int K, int Nn) {
  __shared__ short sAh[64 * GS], sAl[64 * GS], sBh[64 * GS], sBl[64 * GS];
  const int br = blockIdx.z;
  const short* Ahg = AhB + br * sA;
  const short* Alg = AlB + br * sA;
  const short* Bhg = BhB + br * sB;
  const short* Blg = BlB + br * sB;
  float* C = CB + br * sC;
  const int bm = blockIdx.x * 64, bn = blockIdx.y * 64;
  const int t = threadIdx.x;
  const int lane = t & 63, w = t >> 6;
  const int wm = (w & 1) * 32, wn = (w >> 1) * 32;
  const int fr = lane & 15, fq = lane >> 4;
  const int srow = t >> 2, sk = (t & 3) * 8;

  f4 acc[2][2] = {};

  for (int k0 = 0; k0 < K; k0 += 32) {
    const size_t aoff = (size_t)(bm + srow) * K + k0 + sk;
    const size_t boff = (size_t)(bn + srow) * K + k0 + sk;
    bf8 vah = *(const bf8*)&Ahg[aoff];
    bf8 val_ = *(const bf8*)&Alg[aoff];
    bf8 vbh = *(const bf8*)&Bhg[boff];
    bf8 vbl = *(const bf8*)&Blg[boff];
    __syncthreads();
    *(bf8*)&sAh[srow * GS + sk] = vah;
    *(bf8*)&sAl[srow * GS + sk] = val_;
    *(bf8*)&sBh[srow * GS + sk] = vbh;
    *(bf8*)&sBl[srow * GS + sk] = vbl;
    __syncthreads();

    bf8 ah[2], al[2], bh[2], bl[2];
#pragma unroll
    for (int i = 0; i < 2; ++i) {
      ah[i] = *(bf8*)&sAh[(wm + i * 16 + fr) * GS + fq * 8];
      al[i] = *(bf8*)&sAl[(wm + i * 16 + fr) * GS + fq * 8];
      bh[i] = *(bf8*)&sBh[(wn + i * 16 + fr) * GS + fq * 8];
      bl[i] = *(bf8*)&sBl[(wn + i * 16 + fr) * GS + fq * 8];
    }
#pragma unroll
    for (int mi = 0; mi < 2; ++mi)
#pragma unroll
      for (int ni = 0; ni < 2; ++ni) {
        acc[mi][ni] = MFMA_BF16(ah[mi], bh[ni], acc[mi][ni], 0, 0, 0);
        acc[mi][ni] = MFMA_BF16(ah[mi], bl[ni], acc[mi][ni], 0, 0, 0);
        acc[mi][ni] = MFMA_BF16(al[mi], bh[ni], acc[mi][ni], 0, 0, 0);
      }
  }

#pragma unroll
  for (int mi = 0; mi < 2; ++mi)
#pragma unroll
    for (int ni = 0; ni < 2; ++ni) {
      size_t rbase = (size_t)(bm + wm + mi * 16 + fq * 4);
      int cidx = bn + wn + ni * 16 + fr;
#pragma unroll
      for (int r = 0; r < 4; ++r)
        C[(rbase + r) * Nn + cidx] = acc[mi][ni][r];
    }
}

// ---------------------------------------------------------------- final: H_F + student-t q
__global__ __launch_bounds__(256) void final_kernel(
    const float* __restrict__ H1e, const float* __restrict__ H2e,
    const float* __restrict__ mu, float* __restrict__ hf_out,
    float* __restrict__ q_out) {
  int row = (blockIdx.x * blockDim.x + threadIdx.x) >> 6;
  int lane = threadIdx.x & 63;
  float2 h1 = *(const float2*)&H1e[row * 128 + lane * 2];
  float2 h2 = *(const float2*)&H2e[row * 128 + lane * 2];
  float2 hf = make_float2(h1.x + h2.x, h1.y + h2.y);
  *(float2*)&hf_out[row * 128 + lane * 2] = hf;
  float d2[10];
#pragma unroll
  for (int k = 0; k < 10; ++k) {
    float dx = hf.x - mu[k * 128 + lane * 2];
    float dy = hf.y - mu[k * 128 + lane * 2 + 1];
    d2[k] = dx * dx + dy * dy;
  }
#pragma unroll
  for (int k = 0; k < 10; ++k)
#pragma unroll
    for (int o = 32; o; o >>= 1) d2[k] += __shfl_xor(d2[k], o);
  float q[10], s = 0.f;
#pragma unroll
  for (int k = 0; k < 10; ++k) { q[k] = 1.f / (1.f + d2[k]); s += q[k]; }
  float inv = 1.f / s;
  if (lane < 10) q_out[row * 10 + lane] = q[lane] * inv;
}

// ---------------------------------------------------------------- host
extern "C" void kernel_launch(void* const* d_in, const int* in_sizes, int n_in,
                              void* d_out, int out_size, void* d_ws, size_t ws_size,
                              hipStream_t stream) {
  const int D0 = 512, D1 = 256, D2 = 128;
  const int S1 = D0 * D1, S2 = D1 * D2;
  float* out = (float*)d_out;
  const size_t o0 = 0;                       // H_F  [N,128]
  const size_t o1 = o0 + (size_t)NN * 128;   // q    [N,10]
  const size_t o2 = o1 + (size_t)NN * 10;    // H    [N,128]
  const size_t o3 = o2 + (size_t)NN * 128;   // H2   [N,128]
  const size_t o4 = o3 + (size_t)NN * 128;   // X_   [N,512]
  const size_t o5 = o4 + (size_t)NN * 512;   // X_2  [N,512]

  char* w = (char*)d_ws;
  auto alloc = [&](size_t bytes) -> void* {
    void* p = (void*)w;
    w += (bytes + 255) & ~(size_t)255;
    return p;
  };
  // branch-doubled buffers (stride = per-branch size)
  int*   cols  = (int*)  alloc((size_t)2 * NN * CAP * 4);
  float* avals = (float*)alloc((size_t)2 * NN * CAP * 4);
  float* c1v   = (float*)alloc((size_t)2 * NN * CAP * 4);
  float* c2v   = (float*)alloc((size_t)2 * NN * CAP * 4);
  int*   cnt   = (int*)  alloc((size_t)2 * NN * 4);
  float* f1    = (float*)alloc((size_t)2 * NN * 4);
  float* f2    = (float*)alloc((size_t)2 * NN * 4);
  short* Xh    = (short*)alloc((size_t)2 * NN * D0 * 2);
  short* Xl    = (short*)alloc((size_t)2 * NN * D0 * 2);
  float* H1    = (float*)alloc((size_t)2 * NN * D1 * 4);
  short* H1ph  = (short*)alloc((size_t)2 * NN * D1 * 2);
  short* H1pl  = (short*)alloc((size_t)2 * NN * D1 * 2);
  float* H2    = (float*)alloc((size_t)2 * NN * D2 * 4);
  short* Hech  = (short*)alloc((size_t)2 * NN * D2 * 2);
  short* Hecl  = (short*)alloc((size_t)2 * NN * D2 * 2);
  float* dec1  = (float*)alloc((size_t)2 * NN * D1 * 4);
  short* d2h   = (short*)alloc((size_t)2 * NN * D1 * 2);
  short* d2l   = (short*)alloc((size_t)2 * NN * D1 * 2);
  float* dec3  = (float*)alloc((size_t)2 * NN * D0 * 4);
  short* W1h   = (short*)alloc((size_t)2 * S1 * 2);
  short* W1l   = (short*)alloc((size_t)2 * S1 * 2);
  short* W1th  = (short*)alloc((size_t)2 * S1 * 2);
  short* W1tl  = (short*)alloc((size_t)2 * S1 * 2);
  short* W2h   = (short*)alloc((size_t)2 * S2 * 2);
  short* W2l   = (short*)alloc((size_t)2 * S2 * 2);
  short* W2th  = (short*)alloc((size_t)2 * S2 * 2);
  short* W2tl  = (short*)alloc((size_t)2 * S2 * 2);

  const float* A   = (const float*)d_in[0];
  const float* A2  = (const float*)d_in[1];
  const float* X   = (const float*)d_in[2];
  const float* X2  = (const float*)d_in[3];
  const float* W11 = (const float*)d_in[4];
  const float* v111= (const float*)d_in[5];
  const float* v112= (const float*)d_in[6];
  const float* W12 = (const float*)d_in[7];
  const float* v121= (const float*)d_in[8];
  const float* v122= (const float*)d_in[9];
  const float* W21 = (const float*)d_in[10];
  const float* v211= (const float*)d_in[11];
  const float* v212= (const float*)d_in[12];
  const float* W22 = (const float*)d_in[13];
  const float* v221= (const float*)d_in[14];
  const float* v222= (const float*)d_in[15];
  const float* mu  = (const float*)d_in[16];

  const dim3 rows2(NN / 4, 2);

  // 1. weights -> hi/lo (+T)
  convw_all<<<(2 * S1 + 2 * S2) / 256, 256, 0, stream>>>(
      W11, W21, W12, W22, W1h, W1l, W1th, W1tl, W2h, W2l, W2th, W2tl);
  // 2. sparsify both adjacencies
  sparsify2_kernel<<<rows2, 256, 0, stream>>>(A, A2, cols, avals, cnt);
  // 3. X, X2 -> hi/lo
  convX_kernel<<<dim3(NN * D0 / 4 / 256, 2), 256, 0, stream>>>(X, X2, Xh, Xl);
  // 4. H1 = X @ W1  (both branches)
  gemm_nt<<<dim3(NN / 64, D1 / 64, 2), 256, 0, stream>>>(
      Xh, Xl, (size_t)NN * D0, W1th, W1tl, (size_t)S1, H1, (size_t)NN * D1, NN, D0, D1);
  // 5. f1/f2
  fvec_kernel<256><<<rows2, 256, 0, stream>>>(H1, v111, v112, v211, v212, f1, f2);
  // 6. C1 + H1p(hi/lo)
  gatspmm_kernel<256, false><<<rows2, 256, 0, stream>>>(
      cols, avals, cnt, f1, f2, c1v, H1, nullptr, nullptr, H1ph, H1pl);
  // 7. H2 = H1p @ W2
  gemm_nt<<<dim3(NN / 64, D2 / 64, 2), 256, 0, stream>>>(
      H1ph, H1pl, (size_t)NN * D1, W2th, W2tl, (size_t)S2, H2, (size_t)NN * D2, NN, D1, D2);
  // 8. f1/f2 layer2
  fvec_kernel<128><<<rows2, 256, 0, stream>>>(H2, v121, v122, v221, v222, f1, f2);
  // 9. C2 + Henc (f32 -> out slots, hi/lo -> ws)
  gatspmm_kernel<128, true><<<rows2, 256, 0, stream>>>(
      cols, avals, cnt, f1, f2, c2v, H2, out + o2, out + o3, Hech, Hecl);
  // 10. dec1 = Henc @ W2^T
  gemm_nt<<<dim3(NN / 64, D1 / 64, 2), 256, 0, stream>>>(
      Hech, Hecl, (size_t)NN * D2, W2h, W2l, (size_t)S2, dec1, (size_t)NN * D1, NN, D2, D1);
  // 11. dec2 = C2 @ dec1 (hi/lo only)
  spmm_kernel<256, false, true><<<rows2, 256, 0, stream>>>(
      cols, c2v, cnt, dec1, nullptr, nullptr, d2h, d2l);
  // 12. dec3 = dec2 @ W1^T
  gemm_nt<<<dim3(NN / 64, D0 / 64, 2), 256, 0, stream>>>(
      d2h, d2l, (size_t)NN * D1, W1h, W1l, (size_t)S1, dec3, (size_t)NN * D0, NN, D1, D0);
  // 13. X_ = C1 @ dec3 (f32 -> out slots)
  spmm_kernel<512, true, false><<<rows2, 256, 0, stream>>>(
      cols, c1v, cnt, dec3, out + o4, out + o5, nullptr, nullptr);
  // 14. H_F + q
  final_kernel<<<NN / 4, 256, 0, stream>>>(out + o2, out + o3, mu, out + o0, out + o1);
}

// Round 4
// 228.206 us; speedup vs baseline: 2.1888x; 1.3895x over previous
//
#include <hip/hip_runtime.h>
#include <hip/hip_bf16.h>

#define NN 6144
#define CAP 128

typedef short bf8 __attribute__((ext_vector_type(8)));
typedef float f4 __attribute__((ext_vector_type(4)));

__device__ inline unsigned short f2bf(float x) {
  union { float f; unsigned u; } v; v.f = x;
  unsigned r = v.u + 0x7fff + ((v.u >> 16) & 1);
  return (unsigned short)(r >> 16);
}
__device__ inline float bf2f(unsigned short b) {
  union { float f; unsigned u; } v; v.u = ((unsigned)b) << 16;
  return v.f;
}

// ---------------------------------------------------------------- sparsify (MLP-6 prefetch)
__global__ __launch_bounds__(256) void sparsify2_kernel(
    const float* __restrict__ A0, const float* __restrict__ A1,
    int* __restrict__ colsB, float* __restrict__ valsB, int* __restrict__ cntB) {
  const int br = blockIdx.y;
  const float* __restrict__ A = br ? A1 : A0;
  int* cols = colsB + (size_t)br * NN * CAP;
  float* vals = valsB + (size_t)br * NN * CAP;
  int* cnt = cntB + br * NN;
  int row = (blockIdx.x * blockDim.x + threadIdx.x) >> 6;
  int lane = threadIdx.x & 63;
  const float4* __restrict__ arow = (const float4*)(A + (size_t)row * NN);
  int base = 0;
  for (int it = 0; it < 24; it += 6) {
    float4 v[6];
#pragma unroll
    for (int u = 0; u < 6; ++u) v[u] = arow[(it + u) * 64 + lane];
#pragma unroll
    for (int u = 0; u < 6; ++u) {
      float xs[4] = {v[u].x, v[u].y, v[u].z, v[u].w};
      unsigned long long m[4];
#pragma unroll
      for (int q = 0; q < 4; ++q) m[q] = __ballot(xs[q] != 0.0f);
      int off0 = base;
      int off1 = off0 + __popcll(m[0]);
      int off2 = off1 + __popcll(m[1]);
      int off3 = off2 + __popcll(m[2]);
      base = off3 + __popcll(m[3]);
      int offs[4] = {off0, off1, off2, off3};
      unsigned long long lmask = (1ull << lane) - 1ull;
#pragma unroll
      for (int q = 0; q < 4; ++q) {
        if (xs[q] != 0.0f) {
          int idx = offs[q] + __popcll(m[q] & lmask);
          if (idx < CAP) {
            cols[row * CAP + idx] = ((it + u) * 64 + lane) * 4 + q;
            vals[row * CAP + idx] = xs[q];
          }
        }
      }
    }
  }
  if (lane == 0) cnt[row] = base < CAP ? base : CAP;
}

// ---------------------------------------------------------------- all weights -> hi/lo (+transposed)
__global__ __launch_bounds__(256) void convw_all(
    const float* __restrict__ W11, const float* __restrict__ W21,
    const float* __restrict__ W12, const float* __restrict__ W22,
    short* __restrict__ W1h, short* __restrict__ W1l,
    short* __restrict__ W1th, short* __restrict__ W1tl,
    short* __restrict__ W2h, short* __restrict__ W2l,
    short* __restrict__ W2th, short* __restrict__ W2tl) {
  const int S1 = 512 * 256, S2 = 256 * 128;
  int i = blockIdx.x * 256 + threadIdx.x;
  if (i < 2 * S1) {
    int br = i >= S1;
    int idx = br ? i - S1 : i;
    float x = (br ? W21 : W11)[idx];
    unsigned short h = f2bf(x), l = f2bf(x - bf2f(h));
    int r = idx / 256, c = idx % 256;
    size_t o = (size_t)br * S1;
    W1h[o + idx] = (short)h; W1l[o + idx] = (short)l;
    W1th[o + c * 512 + r] = (short)h; W1tl[o + c * 512 + r] = (short)l;
  } else {
    int i2 = i - 2 * S1;
    if (i2 >= 2 * S2) return;
    int br = i2 >= S2;
    int idx = br ? i2 - S2 : i2;
    float x = (br ? W22 : W12)[idx];
    unsigned short h = f2bf(x), l = f2bf(x - bf2f(h));
    int r = idx / 128, c = idx % 128;
    size_t o = (size_t)br * S2;
    W2h[o + idx] = (short)h; W2l[o + idx] = (short)l;
    W2th[o + c * 256 + r] = (short)h; W2tl[o + c * 256 + r] = (short)l;
  }
}

// ---------------------------------------------------------------- X, X2 -> hi/lo
__global__ __launch_bounds__(256) void convX_kernel(
    const float* __restrict__ X0, const float* __restrict__ X1,
    short* __restrict__ XhB, short* __restrict__ XlB) {
  const int br = blockIdx.y;
  const float* __restrict__ in = br ? X1 : X0;
  short* hi = XhB + (size_t)br * NN * 512;
  short* lo = XlB + (size_t)br * NN * 512;
  int i = blockIdx.x * 256 + threadIdx.x;
  float4 v = *(const float4*)&in[i * 4];
  short4 h, l;
  h.x = (short)f2bf(v.x); l.x = (short)f2bf(v.x - bf2f(h.x));
  h.y = (short)f2bf(v.y); l.y = (short)f2bf(v.y - bf2f(h.y));
  h.z = (short)f2bf(v.z); l.z = (short)f2bf(v.z - bf2f(h.z));
  h.w = (short)f2bf(v.w); l.w = (short)f2bf(v.w - bf2f(h.w));
  *(short4*)&hi[i * 4] = h;
  *(short4*)&lo[i * 4] = l;
}

// ---------------------------------------------------------------- f1/f2 = H @ v1, H @ v2
template <int D>
__global__ __launch_bounds__(256) void fvec_kernel(
    const float* __restrict__ HB, const float* __restrict__ v10,
    const float* __restrict__ v20, const float* __restrict__ v11,
    const float* __restrict__ v21, float* __restrict__ f1B, float* __restrict__ f2B) {
  const int br = blockIdx.y;
  const float* H = HB + (size_t)br * NN * D;
  const float* v1 = br ? v11 : v10;
  const float* v2 = br ? v21 : v20;
  float* f1 = f1B + br * NN;
  float* f2 = f2B + br * NN;
  int row = (blockIdx.x * blockDim.x + threadIdx.x) >> 6;
  int lane = threadIdx.x & 63;
  constexpr int E = D / 64;
  const float* hp = H + (size_t)row * D + lane * E;
  float s1 = 0.f, s2 = 0.f;
  if constexpr (E == 4) {
    float4 h = *(const float4*)hp;
    float4 a = *(const float4*)&v1[lane * 4];
    float4 b = *(const float4*)&v2[lane * 4];
    s1 = h.x * a.x + h.y * a.y + h.z * a.z + h.w * a.w;
    s2 = h.x * b.x + h.y * b.y + h.z * b.z + h.w * b.w;
  } else {
    float2 h = *(const float2*)hp;
    float2 a = *(const float2*)&v1[lane * 2];
    float2 b = *(const float2*)&v2[lane * 2];
    s1 = h.x * a.x + h.y * a.y;
    s2 = h.x * b.x + h.y * b.y;
  }
#pragma unroll
  for (int o = 32; o; o >>= 1) {
    s1 += __shfl_xor(s1, o);
    s2 += __shfl_xor(s2, o);
  }
  if (lane == 0) { f1[row] = s1; f2[row] = s2; }
}

// ---------------------------------------------------------------- fused GAT softmax + SPMM (D=128)
// Computes row attention in registers, writes cvals, then out = C @ Hin (Hin width 128).
template <bool WF32, bool WHL>
__global__ __launch_bounds__(256) void gatspmm_kernel(
    const int* __restrict__ colsB, const float* __restrict__ avalsB,
    const int* __restrict__ cntB, const float* __restrict__ f1B,
    const float* __restrict__ f2B, float* __restrict__ cvalsB,
    const float* __restrict__ HinB, float* __restrict__ HoutB,
    short* __restrict__ HhB, short* __restrict__ HlB) {
  const int br = blockIdx.y;
  const int* cols = colsB + (size_t)br * NN * CAP;
  const float* avals = avalsB + (size_t)br * NN * CAP;
  const int* cnt = cntB + br * NN;
  const float* f1 = f1B + br * NN;
  const float* f2 = f2B + br * NN;
  float* cvals = cvalsB + (size_t)br * NN * CAP;
  const float* Hin = HinB + (size_t)br * NN * 128;
  int row = (blockIdx.x * blockDim.x + threadIdx.x) >> 6;
  int lane = threadIdx.x & 63;
  int c = cnt[row];
  float f1i = f1[row];
  const int base = row * CAP;
  float e0 = 0.f, e1 = 0.f;
  int j0 = 0, j1 = 0;
  {
    int k = lane;
    if (k < c) {
      float a = avals[base + k];
      j0 = cols[base + k];
      float lg = a * (f1i + f2[j0]);
      e0 = expf(1.f / (1.f + expf(-lg)));
    }
    k = 64 + lane;
    if (k < c) {
      float a = avals[base + k];
      j1 = cols[base + k];
      float lg = a * (f1i + f2[j1]);
      e1 = expf(1.f / (1.f + expf(-lg)));
    }
  }
  float s = e0 + e1;
#pragma unroll
  for (int o = 32; o; o >>= 1) s += __shfl_xor(s, o);
  float inv = (s == 0.f) ? 1.f : 1.f / s;
  if (lane < c) cvals[base + lane] = e0 * inv;
  if (64 + lane < c) cvals[base + 64 + lane] = e1 * inv;

  float2 acc = make_float2(0.f, 0.f);
  for (int k = 0; k < c; k += 4) {
    float2 h[4]; float cv[4];
#pragma unroll
    for (int u = 0; u < 4; ++u) {
      int kk = k + u;
      if (kk < c) {
        int jj = (kk & 64) ? j1 : j0;
        float ee = (kk & 64) ? e1 : e0;
        int j = __shfl(jj, kk & 63);
        cv[u] = __shfl(ee, kk & 63) * inv;
        h[u] = *(const float2*)&Hin[(size_t)j * 128 + lane * 2];
      }
    }
#pragma unroll
    for (int u = 0; u < 4; ++u) {
      if (k + u < c) { acc.x += cv[u] * h[u].x; acc.y += cv[u] * h[u].y; }
    }
  }
  size_t o = (size_t)br * NN * 128 + (size_t)row * 128 + lane * 2;
  if constexpr (WF32) *(float2*)&HoutB[o] = acc;
  if constexpr (WHL) {
    short2 hh, ll;
    hh.x = (short)f2bf(acc.x); ll.x = (short)f2bf(acc.x - bf2f(hh.x));
    hh.y = (short)f2bf(acc.y); ll.y = (short)f2bf(acc.y - bf2f(hh.y));
    *(short2*)&HhB[o] = hh; *(short2*)&HlB[o] = ll;
  }
}

// ---------------------------------------------------------------- SPMM (D=128): out = C @ Hin
template <bool WF32, bool WHL>
__global__ __launch_bounds__(256) void spmm128_kernel(
    const int* __restrict__ colsB, const float* __restrict__ cvalsB,
    const int* __restrict__ cntB, const float* __restrict__ HinB,
    float* __restrict__ HoutB, short* __restrict__ HhB, short* __restrict__ HlB) {
  const int br = blockIdx.y;
  const int* cols = colsB + (size_t)br * NN * CAP;
  const float* cvals = cvalsB + (size_t)br * NN * CAP;
  const int* cnt = cntB + br * NN;
  const float* Hin = HinB + (size_t)br * NN * 128;
  int row = (blockIdx.x * blockDim.x + threadIdx.x) >> 6;
  int lane = threadIdx.x & 63;
  int c = cnt[row];
  const int base = row * CAP;
  float cv0 = 0.f, cv1 = 0.f;
  int j0 = 0, j1 = 0;
  if (lane < c) { j0 = cols[base + lane]; cv0 = cvals[base + lane]; }
  if (64 + lane < c) { j1 = cols[base + 64 + lane]; cv1 = cvals[base + 64 + lane]; }
  float2 acc = make_float2(0.f, 0.f);
  for (int k = 0; k < c; k += 4) {
    float2 h[4]; float cv[4];
#pragma unroll
    for (int u = 0; u < 4; ++u) {
      int kk = k + u;
      if (kk < c) {
        int jj = (kk & 64) ? j1 : j0;
        float cc = (kk & 64) ? cv1 : cv0;
        int j = __shfl(jj, kk & 63);
        cv[u] = __shfl(cc, kk & 63);
        h[u] = *(const float2*)&Hin[(size_t)j * 128 + lane * 2];
      }
    }
#pragma unroll
    for (int u = 0; u < 4; ++u) {
      if (k + u < c) { acc.x += cv[u] * h[u].x; acc.y += cv[u] * h[u].y; }
    }
  }
  size_t o = (size_t)br * NN * 128 + (size_t)row * 128 + lane * 2;
  if constexpr (WF32) *(float2*)&HoutB[o] = acc;
  if constexpr (WHL) {
    short2 hh, ll;
    hh.x = (short)f2bf(acc.x); ll.x = (short)f2bf(acc.x - bf2f(hh.x));
    hh.y = (short)f2bf(acc.y); ll.y = (short)f2bf(acc.y - bf2f(hh.y));
    *(short2*)&HhB[o] = hh; *(short2*)&HlB[o] = ll;
  }
}

// ---------------------------------------------------------------- split-bf16 MFMA GEMM (NT, batched)
#define GS 40
#define MFMA_BF16 __builtin_amdgcn_mfma_f32_16x16x32_bf16

template <int EPI>  // 0: f32 only, 1: hilo only, 2: both
__global__ __launch_bounds__(256) void gemm_nt(
    const short* __restrict__ AhB, const short* __restrict__ AlB, size_t sA,
    const short* __restrict__ BhB, const short* __restrict__ BlB, size_t sB,
    float* __restrict__ CfB, short* __restrict__ ChB, short* __restrict__ ClB,
    size_t sC, int K, int Nn) {
  __shared__ short sAh[64 * GS], sAl[64 * GS], sBh[64 * GS], sBl[64 * GS];
  const int br = blockIdx.z;
  const short* Ahg = AhB + br * sA;
  const short* Alg = AlB + br * sA;
  const short* Bhg = BhB + br * sB;
  const short* Blg = BlB + br * sB;
  const int bm = blockIdx.x * 64, bn = blockIdx.y * 64;
  const int t = threadIdx.x;
  const int lane = t & 63, w = t >> 6;
  const int wm = (w & 1) * 32, wn = (w >> 1) * 32;
  const int fr = lane & 15, fq = lane >> 4;
  const int srow = t >> 2, sk = (t & 3) * 8;

  f4 acc[2][2] = {};

  for (int k0 = 0; k0 < K; k0 += 32) {
    const size_t aoff = (size_t)(bm + srow) * K + k0 + sk;
    const size_t boff = (size_t)(bn + srow) * K + k0 + sk;
    bf8 vah = *(const bf8*)&Ahg[aoff];
    bf8 val_ = *(const bf8*)&Alg[aoff];
    bf8 vbh = *(const bf8*)&Bhg[boff];
    bf8 vbl = *(const bf8*)&Blg[boff];
    __syncthreads();
    *(bf8*)&sAh[srow * GS + sk] = vah;
    *(bf8*)&sAl[srow * GS + sk] = val_;
    *(bf8*)&sBh[srow * GS + sk] = vbh;
    *(bf8*)&sBl[srow * GS + sk] = vbl;
    __syncthreads();

    bf8 ah[2], al[2], bh[2], bl[2];
#pragma unroll
    for (int i = 0; i < 2; ++i) {
      ah[i] = *(bf8*)&sAh[(wm + i * 16 + fr) * GS + fq * 8];
      al[i] = *(bf8*)&sAl[(wm + i * 16 + fr) * GS + fq * 8];
      bh[i] = *(bf8*)&sBh[(wn + i * 16 + fr) * GS + fq * 8];
      bl[i] = *(bf8*)&sBl[(wn + i * 16 + fr) * GS + fq * 8];
    }
#pragma unroll
    for (int mi = 0; mi < 2; ++mi)
#pragma unroll
      for (int ni = 0; ni < 2; ++ni) {
        acc[mi][ni] = MFMA_BF16(ah[mi], bh[ni], acc[mi][ni], 0, 0, 0);
        acc[mi][ni] = MFMA_BF16(ah[mi], bl[ni], acc[mi][ni], 0, 0, 0);
        acc[mi][ni] = MFMA_BF16(al[mi], bh[ni], acc[mi][ni], 0, 0, 0);
      }
  }

  float* Cf = CfB ? CfB + br * sC : nullptr;
  short* Ch = ChB ? ChB + br * sC : nullptr;
  short* Cl = ClB ? ClB + br * sC : nullptr;
#pragma unroll
  for (int mi = 0; mi < 2; ++mi)
#pragma unroll
    for (int ni = 0; ni < 2; ++ni) {
      int cidx = bn + wn + ni * 16 + fr;
#pragma unroll
      for (int r = 0; r < 4; ++r) {
        size_t off = (size_t)(bm + wm + mi * 16 + fq * 4 + r) * Nn + cidx;
        float x = acc[mi][ni][r];
        if constexpr (EPI != 1) Cf[off] = x;
        if constexpr (EPI >= 1) {
          unsigned short h = f2bf(x);
          Ch[off] = (short)h;
          Cl[off] = (short)f2bf(x - bf2f(h));
        }
      }
    }
}

// ---------------------------------------------------------------- final: H_F + student-t q
__global__ __launch_bounds__(256) void final_kernel(
    const float* __restrict__ H1e, const float* __restrict__ H2e,
    const float* __restrict__ mu, float* __restrict__ hf_out,
    float* __restrict__ q_out) {
  int row = (blockIdx.x * blockDim.x + threadIdx.x) >> 6;
  int lane = threadIdx.x & 63;
  float2 h1 = *(const float2*)&H1e[row * 128 + lane * 2];
  float2 h2 = *(const float2*)&H2e[row * 128 + lane * 2];
  float2 hf = make_float2(h1.x + h2.x, h1.y + h2.y);
  *(float2*)&hf_out[row * 128 + lane * 2] = hf;
  float d2[10];
#pragma unroll
  for (int k = 0; k < 10; ++k) {
    float dx = hf.x - mu[k * 128 + lane * 2];
    float dy = hf.y - mu[k * 128 + lane * 2 + 1];
    d2[k] = dx * dx + dy * dy;
  }
#pragma unroll
  for (int k = 0; k < 10; ++k)
#pragma unroll
    for (int o = 32; o; o >>= 1) d2[k] += __shfl_xor(d2[k], o);
  float q[10], s = 0.f;
#pragma unroll
  for (int k = 0; k < 10; ++k) { q[k] = 1.f / (1.f + d2[k]); s += q[k]; }
  float inv = 1.f / s;
  if (lane < 10) q_out[row * 10 + lane] = q[lane] * inv;
}

// ---------------------------------------------------------------- host
extern "C" void kernel_launch(void* const* d_in, const int* in_sizes, int n_in,
                              void* d_out, int out_size, void* d_ws, size_t ws_size,
                              hipStream_t stream) {
  const int D0 = 512, D1 = 256, D2 = 128;
  const int S1 = D0 * D1, S2 = D1 * D2;
  float* out = (float*)d_out;
  const size_t o0 = 0;                       // H_F  [N,128]
  const size_t o1 = o0 + (size_t)NN * 128;   // q    [N,10]
  const size_t o2 = o1 + (size_t)NN * 10;    // H    [N,128]
  const size_t o3 = o2 + (size_t)NN * 128;   // H2   [N,128]
  const size_t o4 = o3 + (size_t)NN * 128;   // X_   [N,512]
  const size_t o5 = o4 + (size_t)NN * 512;   // X_2  [N,512]

  char* w = (char*)d_ws;
  auto alloc = [&](size_t bytes) -> void* {
    void* p = (void*)w;
    w += (bytes + 255) & ~(size_t)255;
    return p;
  };
  int*   cols  = (int*)  alloc((size_t)2 * NN * CAP * 4);
  float* avals = (float*)alloc((size_t)2 * NN * CAP * 4);
  float* c1v   = (float*)alloc((size_t)2 * NN * CAP * 4);
  float* c2v   = (float*)alloc((size_t)2 * NN * CAP * 4);
  int*   cnt   = (int*)  alloc((size_t)2 * NN * 4);
  float* f1    = (float*)alloc((size_t)2 * NN * 4);
  float* f2    = (float*)alloc((size_t)2 * NN * 4);
  short* Xh    = (short*)alloc((size_t)2 * NN * D0 * 2);
  short* Xl    = (short*)alloc((size_t)2 * NN * D0 * 2);
  float* H1    = (float*)alloc((size_t)2 * NN * D1 * 4);
  short* H1h   = (short*)alloc((size_t)2 * NN * D1 * 2);
  short* H1l   = (short*)alloc((size_t)2 * NN * D1 * 2);
  float* G1    = (float*)alloc((size_t)2 * NN * D2 * 4);
  float* H2    = (float*)alloc((size_t)2 * NN * D2 * 4);
  float* C2s   = (float*)alloc((size_t)2 * NN * D2 * 4);
  short* Cth   = (short*)alloc((size_t)2 * NN * D2 * 2);
  short* Ctl   = (short*)alloc((size_t)2 * NN * D2 * 2);
  short* Uh    = (short*)alloc((size_t)2 * NN * D1 * 2);
  short* Ul    = (short*)alloc((size_t)2 * NN * D1 * 2);
  short* W1h   = (short*)alloc((size_t)2 * S1 * 2);
  short* W1l   = (short*)alloc((size_t)2 * S1 * 2);
  short* W1th  = (short*)alloc((size_t)2 * S1 * 2);
  short* W1tl  = (short*)alloc((size_t)2 * S1 * 2);
  short* W2h   = (short*)alloc((size_t)2 * S2 * 2);
  short* W2l   = (short*)alloc((size_t)2 * S2 * 2);
  short* W2th  = (short*)alloc((size_t)2 * S2 * 2);
  short* W2tl  = (short*)alloc((size_t)2 * S2 * 2);

  const float* A   = (const float*)d_in[0];
  const float* A2  = (const float*)d_in[1];
  const float* X   = (const float*)d_in[2];
  const float* X2  = (const float*)d_in[3];
  const float* W11 = (const float*)d_in[4];
  const float* v111= (const float*)d_in[5];
  const float* v112= (const float*)d_in[6];
  const float* v121= (const float*)d_in[8];
  const float* v122= (const float*)d_in[9];
  const float* W21 = (const float*)d_in[10];
  const float* v211= (const float*)d_in[11];
  const float* v212= (const float*)d_in[12];
  const float* v221= (const float*)d_in[14];
  const float* v222= (const float*)d_in[15];
  const float* W12 = (const float*)d_in[7];
  const float* W22 = (const float*)d_in[13];
  const float* mu  = (const float*)d_in[16];

  const dim3 rows2(NN / 4, 2);

  // 1. weights -> hi/lo (+T)
  convw_all<<<(2 * S1 + 2 * S2) / 256, 256, 0, stream>>>(
      W11, W21, W12, W22, W1h, W1l, W1th, W1tl, W2h, W2l, W2th, W2tl);
  // 2. sparsify
  sparsify2_kernel<<<rows2, 256, 0, stream>>>(A, A2, cols, avals, cnt);
  // 3. X -> hi/lo
  convX_kernel<<<dim3(NN * D0 / 4 / 256, 2), 256, 0, stream>>>(X, X2, Xh, Xl);
  // 4. H1 = X @ W11  (f32 + hi/lo)
  gemm_nt<2><<<dim3(NN / 64, D1 / 64, 2), 256, 0, stream>>>(
      Xh, Xl, (size_t)NN * D0, W1th, W1tl, (size_t)S1, H1, H1h, H1l,
      (size_t)NN * D1, D0, D1);
  // 5. f1/f2 layer1 (from H1)
  fvec_kernel<256><<<rows2, 256, 0, stream>>>(H1, v111, v112, v211, v212, f1, f2);
  // 6. G1 = H1 @ W12 (f32)
  gemm_nt<0><<<dim3(NN / 64, D2 / 64, 2), 256, 0, stream>>>(
      H1h, H1l, (size_t)NN * D1, W2th, W2tl, (size_t)S2, G1, nullptr, nullptr,
      (size_t)NN * D2, D1, D2);
  // 7. C1 (cvals=c1v) + H2 = C1 @ G1 (f32)
  gatspmm_kernel<true, false><<<rows2, 256, 0, stream>>>(
      cols, avals, cnt, f1, f2, c1v, G1, H2, nullptr, nullptr);
  // 8. f1/f2 layer2 (from H2)
  fvec_kernel<128><<<rows2, 256, 0, stream>>>(H2, v121, v122, v221, v222, f1, f2);
  // 9. C2 (cvals=c2v) + Henc = C2 @ H2 -> out slots o2/o3
  gatspmm_kernel<true, false><<<rows2, 256, 0, stream>>>(
      cols, avals, cnt, f1, f2, c2v, H2, out + o2, nullptr, nullptr);
  // 10. C2s = C2 @ Henc (f32)
  spmm128_kernel<true, false><<<rows2, 256, 0, stream>>>(
      cols, c2v, cnt, out + o2, C2s, nullptr, nullptr);
  // 11. Ct = C1 @ C2s (hi/lo)
  spmm128_kernel<false, true><<<rows2, 256, 0, stream>>>(
      cols, c1v, cnt, C2s, nullptr, Cth, Ctl);
  // 12. U = Ct @ W2^T (hi/lo)   [Bt = W2 row-major: [256,128]=[Nn,K]]
  gemm_nt<1><<<dim3(NN / 64, D1 / 64, 2), 256, 0, stream>>>(
      Cth, Ctl, (size_t)NN * D2, W2h, W2l, (size_t)S2, nullptr, Uh, Ul,
      (size_t)NN * D1, D2, D1);
  // 13. X_ = U @ W1^T (f32 -> out o4/o5)  [Bt = W1 row-major: [512,256]=[Nn,K]]
  gemm_nt<0><<<dim3(NN / 64, D0 / 64, 2), 256, 0, stream>>>(
      Uh, Ul, (size_t)NN * D1, W1h, W1l, (size_t)S1, out + o4, nullptr, nullptr,
      (size_t)NN * D0, D1, D0);
  // 14. H_F + q
  final_kernel<<<NN / 4, 256, 0, stream>>>(out + o2, out + o3, mu, out + o0, out + o1);
}